// Round 2
// baseline (1051.820 us; speedup 1.0000x reference)
//
#include <hip/hip_runtime.h>
#include <hip/hip_bf16.h>
#include <hip/hip_cooperative_groups.h>

namespace cg = cooperative_groups;

#define LRELU_ALPHA 0.3f
#define LN_EPS 1e-3f

typedef short bf16x8 __attribute__((ext_vector_type(8)));
typedef float f32x4 __attribute__((ext_vector_type(4)));

static __device__ __forceinline__ unsigned short f2bf(float f) {
    union { float f; unsigned u; } v; v.f = f;
    unsigned r = v.u + 0x7fffu + ((v.u >> 16) & 1u);  // RNE
    return (unsigned short)(r >> 16);
}

// async 16B global -> LDS (DMA). LDS dest = wave-uniform base + lane*16.
#define ASYNC_CP16(gsrc, ldst)                                                  \
    __builtin_amdgcn_global_load_lds(                                           \
        (const __attribute__((address_space(1))) unsigned int*)(gsrc),          \
        (__attribute__((address_space(3))) unsigned int*)(ldst), 16, 0, 0)

#define NE 1152   // extended B-rows: 1024 hidden + 15 fused-skinny + pad
#define NB 1152   // cooperative grid size (== GEMM tile count, 4.5 blocks/CU)

// ===========================================================================
// ====================  MEGA (single cooperative kernel)  ===================
// ===========================================================================
// Phases (6 grid.sync()s replace 7 kernel boundaries):
//  P0: prep for layer 0 (x cast, w0a transpose, wcomb0, be0)      2693 units
//  P1: gemm0 (1 tile/block) + OVERLAPPED layer-1 prep (w1a T,
//      wcomb1, be1)                                               1152+1318
//  P2: diversity0 (1024 virtual blocks: 512 i-tiles x 2 j-chunks)
//  P3: ln_mid (rows grid-strided)
//  P4: gemm1 (1 tile/block)
//  P5: diversity1
//  P6: ln_head
// Budget: __launch_bounds__(256,5) -> <=102 VGPR, 16KB LDS -> 5 blocks/CU
// co-resident (LDS 80KB/160, threads 1280/2048) so 1152 blocks fit.
// Diversity uses 2 i-rows/wave (R1 showed 2-row == 4-row perf) to stay
// under the VGPR cap without spill.
// ---------------------------------------------------------------------------

// ---- prep units, layer-0 set (u in [0,2693)) ----
static __device__ __forceinline__ void prep0_unit(
        int u, int tid, void* smem,
        const float* __restrict__ x, const float* __restrict__ w0a,
        const float* __restrict__ b0a, const float* __restrict__ w0b,
        const float* __restrict__ b0b,
        unsigned short* __restrict__ x_bf, unsigned short* __restrict__ bT0,
        float* __restrict__ be0) {
    if (u < 2048) {                        // cast x -> bf16
        const int i = (u * 256 + tid) * 4;
        const float4 v = *(const float4*)(x + i);
        ushort4 o;
        o.x = f2bf(v.x); o.y = f2bf(v.y); o.z = f2bf(v.z); o.w = f2bf(v.w);
        *(ushort4*)(x_bf + i) = o;
    } else if (u < 2560) {                 // transpose w0a -> bT0
        float (*tile)[33] = (float(*)[33])smem;
        const int b2 = u - 2048;
        const int nb = (b2 & 31) * 32, kb = (b2 >> 5) * 32;
        const int tx = tid & 31, ty = tid >> 5;       // 32 x 8
#pragma unroll
        for (int i = 0; i < 4; ++i)
            tile[ty + i * 8][tx] = w0a[(size_t)(kb + ty + i * 8) * 1024 + nb + tx];
        __syncthreads();
#pragma unroll
        for (int i = 0; i < 4; ++i)
            bT0[(size_t)(nb + ty + i * 8) * 512 + kb + tx] = f2bf(tile[tx][ty + i * 8]);
    } else if (u < 2689) {                 // wcomb0: skinny fold into B rows 1024..1038
        const int b4 = u - 2560;
        const int w = tid >> 6, lane = tid & 63;
        const int row = b4 * 4 + w;
        if (row <= 512) {                  // NO early return (grid.sync safety)
            const float* src = (row < 512) ? (w0a + (size_t)row * 1024) : b0a;
            float acc[15] = {};
            for (int hh = lane; hh < 1024; hh += 64) {
                const float a = src[hh];
                const float* wr = w0b + hh * 15;
#pragma unroll
                for (int c = 0; c < 15; ++c) acc[c] += a * wr[c];
            }
#pragma unroll
            for (int c = 0; c < 15; ++c)
#pragma unroll
                for (int off = 32; off > 0; off >>= 1) acc[c] += __shfl_xor(acc[c], off, 64);
            if (lane < 15) {
                if (row < 512) bT0[(size_t)(1024 + lane) * 512 + row] = f2bf(acc[lane]);
                else           be0[1024 + lane] = acc[lane] + b0b[lane];
            }
        }
    } else {                               // be0 bias copy (4 units)
        const int b6 = u - 2689;
        be0[b6 * 256 + tid] = b0a[b6 * 256 + tid];
    }
}

// ---- prep units, layer-1 set (u in [0,1318)) — overlapped with gemm0 ----
static __device__ __forceinline__ void prep1_unit(
        int u, int tid, void* smem,
        const float* __restrict__ w1a, const float* __restrict__ b1a,
        const float* __restrict__ w1b, const float* __restrict__ b1b,
        unsigned short* __restrict__ bT1, float* __restrict__ be1) {
    if (u < 1056) {                        // transpose w1a -> bT1
        float (*tile)[33] = (float(*)[33])smem;
        const int nb = (u & 31) * 32, kb = (u >> 5) * 32;   // kb up to 1055
        const int tx = tid & 31, ty = tid >> 5;
#pragma unroll
        for (int i = 0; i < 4; ++i) {
            const int k = kb + ty + i * 8;
            tile[ty + i * 8][tx] = (k < 1029) ? w1a[(size_t)k * 1024 + nb + tx] : 0.f;
        }
        __syncthreads();
#pragma unroll
        for (int i = 0; i < 4; ++i)
            bT1[(size_t)(nb + ty + i * 8) * 1056 + kb + tx] = f2bf(tile[tx][ty + i * 8]);
    } else if (u < 1314) {                 // wcomb1
        const int b4 = u - 1056;
        const int w = tid >> 6, lane = tid & 63;
        const int row = b4 * 4 + w;
        if (row <= 1029) {
            const float* src = (row < 1029) ? (w1a + (size_t)row * 1024) : b1a;
            float acc[15] = {};
            for (int hh = lane; hh < 1024; hh += 64) {
                const float a = src[hh];
                const float* wr = w1b + hh * 15;
#pragma unroll
                for (int c = 0; c < 15; ++c) acc[c] += a * wr[c];
            }
#pragma unroll
            for (int c = 0; c < 15; ++c)
#pragma unroll
                for (int off = 32; off > 0; off >>= 1) acc[c] += __shfl_xor(acc[c], off, 64);
            if (lane < 15) {
                if (row < 1029) bT1[(size_t)(1024 + lane) * 1056 + row] = f2bf(acc[lane]);
                else            be1[1024 + lane] = acc[lane] + b1b[lane];
            }
        }
    } else {                               // be1 bias copy (4 units)
        const int b6 = u - 1314;
        be1[b6 * 256 + tid] = b1a[b6 * 256 + tid];
    }
}

// ---- one 64x64 GEMM tile (2-phase LDS double buffer, As/Bs in smem) ----
static __device__ __forceinline__ void gemm_tile(
        int tt, int tid, unsigned short* As, unsigned short* Bs,
        const unsigned short* __restrict__ A, int lda,
        const unsigned short* __restrict__ BT, int ldb,
        const float* __restrict__ bias, float* __restrict__ C,
        float* __restrict__ tdiv, int K) {
    const int w = tid >> 6, lane = tid & 63;
    const int q = lane >> 4, m16 = lane & 15;
    const int wr = (w >> 1) * 32, wc = (w & 1) * 32;
    const int bx = tt % 18, by = tt / 18;
    const int br = by * 64, bc = bx * 64;
    const int sr = tid >> 2, sc = (tid & 3) * 8;

    const unsigned short* gA0 = A + (size_t)(br + sr) * lda + sc;
    const unsigned short* gB0 = BT + (size_t)(bc + sr) * ldb + sc;

    f32x4 acc[2][2] = {};

    ASYNC_CP16(gA0, As + tid * 8);
    ASYNC_CP16(gB0, Bs + tid * 8);
    __syncthreads();

    int cur = 0;
    for (int k0 = 0; k0 < K; k0 += 32) {
        if (k0 + 32 < K) {
            ASYNC_CP16(gA0 + k0 + 32, As + (cur ^ 1) * 2048 + tid * 8);
            ASYNC_CP16(gB0 + k0 + 32, Bs + (cur ^ 1) * 2048 + tid * 8);
        }
        bf16x8 af[2], bfr[2];
#pragma unroll
        for (int i = 0; i < 2; ++i)
            af[i] = *(const bf16x8*)(As + cur * 2048 + (wr + 16 * i + m16) * 32 + q * 8);
#pragma unroll
        for (int j = 0; j < 2; ++j)
            bfr[j] = *(const bf16x8*)(Bs + cur * 2048 + (wc + 16 * j + m16) * 32 + q * 8);
#pragma unroll
        for (int i = 0; i < 2; ++i)
#pragma unroll
            for (int j = 0; j < 2; ++j)
                acc[i][j] = __builtin_amdgcn_mfma_f32_16x16x32_bf16(af[i], bfr[j], acc[i][j], 0, 0, 0);
        __syncthreads();
        cur ^= 1;
    }

#pragma unroll
    for (int i = 0; i < 2; ++i) {
        const int gr = br + wr + 16 * i + q * 4;
#pragma unroll
        for (int j = 0; j < 2; ++j) {
            const int gc = bc + wc + 16 * j + m16;
            if (gc < 1024) {
                const float b = bias[gc];
#pragma unroll
                for (int r = 0; r < 4; ++r)
                    C[(size_t)(gr + r) * 1024 + gc] = acc[i][j][r] + b;
            } else if (gc < 1039) {
                const float b = bias[gc];
#pragma unroll
                for (int r = 0; r < 4; ++r)
                    tdiv[(size_t)(gr + r) * 15 + (gc - 1024)] = acc[i][j][r] + b;
            }
        }
    }
}

// ---- diversity: 2 i-rows/wave, 8 rows/block, 2 j-chunks (<=102 VGPR) ----
static __device__ __forceinline__ void div_block(
        int vb, int tid, float* tj_s,
        const float* __restrict__ tdiv, float* __restrict__ dvp) {
    const int lane = tid & 63, g = tid >> 6;
    const int i0 = (vb & 511) * 8 + g * 2;
    const int jc = vb >> 9;
    const int jbeg = jc * 2048, jend = jbeg + 2048;

    float ti[2][15];
#pragma unroll
    for (int r = 0; r < 2; ++r)
#pragma unroll
        for (int d = 0; d < 15; ++d)
            ti[r][d] = tdiv[(i0 + r) * 15 + d];

    float acc[2][5] = {};

    for (int j0 = jbeg; j0 < jend; j0 += 256) {
        __syncthreads();
#pragma unroll
        for (int it = 0; it < 15; ++it)
            tj_s[it * 256 + tid] = tdiv[j0 * 15 + it * 256 + tid];
        __syncthreads();
#pragma unroll
        for (int m = 0; m < 4; ++m) {
            const float* rp = tj_s + (m * 64 + lane) * 15;
#pragma unroll
            for (int r = 0; r < 2; ++r) {
#pragma unroll
                for (int k = 0; k < 5; ++k) {
                    const float s = fabsf(ti[r][3 * k]     - rp[3 * k])
                                  + fabsf(ti[r][3 * k + 1] - rp[3 * k + 1])
                                  + fabsf(ti[r][3 * k + 2] - rp[3 * k + 2]);
                    acc[r][k] += __expf(-s);
                }
            }
        }
    }

#pragma unroll
    for (int r = 0; r < 2; ++r)
#pragma unroll
        for (int k = 0; k < 5; ++k)
#pragma unroll
            for (int off = 32; off > 0; off >>= 1)
                acc[r][k] += __shfl_xor(acc[r][k], off, 64);

    if (lane == 0) {
        float* dst = dvp + (size_t)jc * 4096 * 5;
#pragma unroll
        for (int r = 0; r < 2; ++r)
#pragma unroll
            for (int k = 0; k < 5; ++k)
                dst[(i0 + r) * 5 + k] = acc[r][k];
    }
}

// ---- LN(center) + LeakyReLU rows (mega versions, 2 dvp slots) ----
static __device__ __forceinline__ void ln_mid_row(
        int i, int tid, float* rsm,
        const float* __restrict__ h, const float* __restrict__ dvp,
        const float* __restrict__ beta, unsigned short* __restrict__ out_bf) {
    const int C = 1029, H = 1024, Cp = 1056;
    float v[5];
    float s = 0.f, s2 = 0.f;
#pragma unroll
    for (int r = 0; r < 5; ++r) {
        const int c = tid + r * 256;
        if (c < C) {
            float x;
            if (c < H) x = h[(size_t)i * H + c];
            else {
                const int k = c - H;
                x = dvp[(size_t)i * 5 + k] + dvp[(size_t)4096 * 5 + i * 5 + k];
            }
            v[r] = x; s += x; s2 += x * x;
        }
    }
    const int lane = tid & 63, wave = tid >> 6;
#pragma unroll
    for (int off = 32; off > 0; off >>= 1) {
        s += __shfl_down(s, off, 64);
        s2 += __shfl_down(s2, off, 64);
    }
    if (lane == 0) { rsm[wave] = s; rsm[4 + wave] = s2; }
    __syncthreads();
    const float S  = rsm[0] + rsm[1] + rsm[2] + rsm[3];
    const float S2 = rsm[4] + rsm[5] + rsm[6] + rsm[7];
    const float mu = S / (float)C;
    const float var = S2 / (float)C - mu * mu;
    const float rstd = rsqrtf(var + LN_EPS);
#pragma unroll
    for (int r = 0; r < 5; ++r) {
        const int c = tid + r * 256;
        if (c < C) {
            float y = (v[r] - mu) * rstd + beta[c];
            y = (y >= 0.f) ? y : LRELU_ALPHA * y;
            out_bf[(size_t)i * Cp + c] = f2bf(y);
        } else if (c < Cp) {
            out_bf[(size_t)i * Cp + c] = 0;
        }
    }
    __syncthreads();   // protect rsm reuse across grid-strided rows
}

static __device__ __forceinline__ void ln_head_row(
        int i, int tid, float* rsm,
        const float* __restrict__ h, const float* __restrict__ dvp,
        const float* __restrict__ beta, const float* __restrict__ wf,
        const float* __restrict__ bfp, float* __restrict__ out) {
    const int C = 1029, H = 1024;
    float v[5];
    float s = 0.f, s2 = 0.f;
#pragma unroll
    for (int r = 0; r < 5; ++r) {
        const int c = tid + r * 256;
        if (c < C) {
            float x;
            if (c < H) x = h[(size_t)i * H + c];
            else {
                const int k = c - H;
                x = dvp[(size_t)i * 5 + k] + dvp[(size_t)4096 * 5 + i * 5 + k];
            }
            v[r] = x; s += x; s2 += x * x;
        }
    }
    const int lane = tid & 63, wave = tid >> 6;
#pragma unroll
    for (int off = 32; off > 0; off >>= 1) {
        s += __shfl_down(s, off, 64);
        s2 += __shfl_down(s2, off, 64);
    }
    if (lane == 0) { rsm[wave] = s; rsm[4 + wave] = s2; }
    __syncthreads();
    const float S  = rsm[0] + rsm[1] + rsm[2] + rsm[3];
    const float S2 = rsm[4] + rsm[5] + rsm[6] + rsm[7];
    const float mu = S / (float)C;
    const float var = S2 / (float)C - mu * mu;
    const float rstd = rsqrtf(var + LN_EPS);
    float hsum = 0.f;
#pragma unroll
    for (int r = 0; r < 5; ++r) {
        const int c = tid + r * 256;
        if (c < C) {
            float y = (v[r] - mu) * rstd + beta[c];
            y = (y >= 0.f) ? y : LRELU_ALPHA * y;
            hsum += y * wf[c];
        }
    }
#pragma unroll
    for (int off = 32; off > 0; off >>= 1) hsum += __shfl_down(hsum, off, 64);
    if (lane == 0) rsm[8 + wave] = hsum;
    __syncthreads();
    if (tid == 0) out[i] = rsm[8] + rsm[9] + rsm[10] + rsm[11] + bfp[0];
    __syncthreads();
}

__global__ __launch_bounds__(256, 5)
void mega_kernel(const float* __restrict__ x,
                 const float* __restrict__ w0a, const float* __restrict__ b0a,
                 const float* __restrict__ w0b, const float* __restrict__ b0b,
                 const float* __restrict__ w1a, const float* __restrict__ b1a,
                 const float* __restrict__ w1b, const float* __restrict__ b1b,
                 const float* __restrict__ beta0, const float* __restrict__ beta1,
                 const float* __restrict__ wf, const float* __restrict__ bfp,
                 float* __restrict__ out,
                 float* __restrict__ h, float* __restrict__ tdiv,
                 float* __restrict__ dvp, float* __restrict__ be0,
                 float* __restrict__ be1,
                 unsigned short* __restrict__ x_bf, unsigned short* __restrict__ hc_bf,
                 unsigned short* __restrict__ bT0, unsigned short* __restrict__ bT1) {
    cg::grid_group gg = cg::this_grid();
    const int bid = blockIdx.x, tid = threadIdx.x;
    __shared__ __align__(16) unsigned char smem[16384];
    unsigned short* As = (unsigned short*)smem;        // 2 x 2048 shorts (8 KB)
    unsigned short* Bs = As + 4096;                    // 2 x 2048 shorts (8 KB)
    float* tj_s = (float*)smem;                        // 256*15 floats (15 KB)
    float* rsm  = (float*)smem;                        // 12 floats (ln reductions)

    // ---- P0: layer-0 prep ----
    for (int u = bid; u < 2693; u += NB) {
        prep0_unit(u, tid, smem, x, w0a, b0a, w0b, b0b, x_bf, bT0, be0);
        __syncthreads();
    }
    gg.sync();

    // ---- P1: gemm0 (one tile each) + overlapped layer-1 prep ----
    gemm_tile(bid, tid, As, Bs, x_bf, 512, bT0, 512, be0, h, tdiv, 512);
    __syncthreads();
    for (int u = bid; u < 1318; u += NB) {
        prep1_unit(u, tid, smem, w1a, b1a, w1b, b1b, bT1, be1);
        __syncthreads();
    }
    gg.sync();

    // ---- P2: diversity0 ----
    if (bid < 1024) div_block(bid, tid, tj_s, tdiv, dvp);
    gg.sync();

    // ---- P3: LN + lrelu -> hc_bf ----
    for (int r = bid; r < 4096; r += NB)
        ln_mid_row(r, tid, rsm, h, dvp, beta0, hc_bf);
    gg.sync();

    // ---- P4: gemm1 ----
    gemm_tile(bid, tid, As, Bs, hc_bf, 1056, bT1, 1056, be1, h, tdiv, 1056);
    gg.sync();

    // ---- P5: diversity1 ----
    if (bid < 1024) div_block(bid, tid, tj_s, tdiv, dvp);
    gg.sync();

    // ---- P6: LN + lrelu + head dot -> out ----
    for (int r = bid; r < 4096; r += NB)
        ln_head_row(r, tid, rsm, h, dvp, beta1, wf, bfp, out);
}

// ===========================================================================
// ================  FALLBACK: proven Round-1 8-kernel pipeline  =============
// ===========================================================================
__global__ void prep_kernel(const float* __restrict__ x,
                            const float* __restrict__ w0a, const float* __restrict__ b0a,
                            const float* __restrict__ w0b, const float* __restrict__ b0b,
                            const float* __restrict__ w1a, const float* __restrict__ b1a,
                            const float* __restrict__ w1b, const float* __restrict__ b1b,
                            unsigned short* __restrict__ x_bf,
                            unsigned short* __restrict__ bT0, unsigned short* __restrict__ bT1,
                            float* __restrict__ be0, float* __restrict__ be1) {
    __shared__ float tile[32][33];
    const int b = blockIdx.x, tid = threadIdx.x;

    if (b < 2048) {
        const int i = (b * 256 + tid) * 4;
        const float4 v = *(const float4*)(x + i);
        ushort4 o;
        o.x = f2bf(v.x); o.y = f2bf(v.y); o.z = f2bf(v.z); o.w = f2bf(v.w);
        *(ushort4*)(x_bf + i) = o;
        return;
    }
    if (b < 2560) {
        const int b2 = b - 2048;
        const int nb = (b2 & 31) * 32, kb = (b2 >> 5) * 32;
        const int tx = tid & 31, ty = tid >> 5;
#pragma unroll
        for (int i = 0; i < 4; ++i)
            tile[ty + i * 8][tx] = w0a[(size_t)(kb + ty + i * 8) * 1024 + nb + tx];
        __syncthreads();
#pragma unroll
        for (int i = 0; i < 4; ++i)
            bT0[(size_t)(nb + ty + i * 8) * 512 + kb + tx] = f2bf(tile[tx][ty + i * 8]);
        return;
    }
    if (b < 3616) {
        const int b3 = b - 2560;
        const int nb = (b3 & 31) * 32, kb = (b3 >> 5) * 32;
        const int tx = tid & 31, ty = tid >> 5;
#pragma unroll
        for (int i = 0; i < 4; ++i) {
            const int k = kb + ty + i * 8;
            tile[ty + i * 8][tx] = (k < 1029) ? w1a[(size_t)k * 1024 + nb + tx] : 0.f;
        }
        __syncthreads();
#pragma unroll
        for (int i = 0; i < 4; ++i)
            bT1[(size_t)(nb + ty + i * 8) * 1056 + kb + tx] = f2bf(tile[tx][ty + i * 8]);
        return;
    }
    if (b < 4003) {
        const int is1 = (b >= 3745);
        const int b4 = b - (is1 ? 3745 : 3616);
        const int w = tid >> 6, lane = tid & 63;
        const int row = b4 * 4 + w;
        const int F = is1 ? 1029 : 512;
        if (row > F) return;
        const float* wa = is1 ? w1a : w0a;
        const float* ba = is1 ? b1a : b0a;
        const float* wb = is1 ? w1b : w0b;
        const float* bb = is1 ? b1b : b0b;
        const float* src = (row < F) ? (wa + (size_t)row * 1024) : ba;
        float acc[15] = {};
        for (int hh = lane; hh < 1024; hh += 64) {
            const float a = src[hh];
            const float* wr = wb + hh * 15;
#pragma unroll
            for (int c = 0; c < 15; ++c) acc[c] += a * wr[c];
        }
#pragma unroll
        for (int c = 0; c < 15; ++c)
#pragma unroll
            for (int off = 32; off > 0; off >>= 1) acc[c] += __shfl_xor(acc[c], off, 64);
        if (lane < 15) {
            if (row < F) {
                if (is1) bT1[(size_t)(1024 + lane) * 1056 + row] = f2bf(acc[lane]);
                else     bT0[(size_t)(1024 + lane) * 512  + row] = f2bf(acc[lane]);
            } else {
                if (is1) be1[1024 + lane] = acc[lane] + bb[lane];
                else     be0[1024 + lane] = acc[lane] + bb[lane];
            }
        }
        return;
    }
    {
        const int b6 = b - 4003;
        if (b6 < 4) be0[b6 * 256 + tid] = b0a[b6 * 256 + tid];
        else        be1[(b6 - 4) * 256 + tid] = b1a[(b6 - 4) * 256 + tid];
    }
}

__global__ __launch_bounds__(256)
void mfma_gemm(const unsigned short* __restrict__ A, int lda,
               const unsigned short* __restrict__ BT, int ldb,
               const float* __restrict__ bias, float* __restrict__ C,
               float* __restrict__ t, int K) {
    __shared__ unsigned short As[2][64 * 32];
    __shared__ unsigned short Bs[2][64 * 32];
    const int tid = threadIdx.x;
    const int w = tid >> 6, lane = tid & 63;
    const int q = lane >> 4, m16 = lane & 15;
    const int wr = (w >> 1) * 32, wc = (w & 1) * 32;
    const int br = blockIdx.y * 64, bc = blockIdx.x * 64;
    const int sr = tid >> 2, sc = (tid & 3) * 8;

    const unsigned short* gA0 = A + (size_t)(br + sr) * lda + sc;
    const unsigned short* gB0 = BT + (size_t)(bc + sr) * ldb + sc;

    f32x4 acc[2][2] = {};

    ASYNC_CP16(gA0, &As[0][tid * 8]);
    ASYNC_CP16(gB0, &Bs[0][tid * 8]);
    __syncthreads();

    int cur = 0;
    for (int k0 = 0; k0 < K; k0 += 32) {
        if (k0 + 32 < K) {
            ASYNC_CP16(gA0 + k0 + 32, &As[cur ^ 1][tid * 8]);
            ASYNC_CP16(gB0 + k0 + 32, &Bs[cur ^ 1][tid * 8]);
        }
        bf16x8 af[2], bfr[2];
#pragma unroll
        for (int i = 0; i < 2; ++i)
            af[i] = *(const bf16x8*)(&As[cur][(wr + 16 * i + m16) * 32 + q * 8]);
#pragma unroll
        for (int j = 0; j < 2; ++j)
            bfr[j] = *(const bf16x8*)(&Bs[cur][(wc + 16 * j + m16) * 32 + q * 8]);
#pragma unroll
        for (int i = 0; i < 2; ++i)
#pragma unroll
            for (int j = 0; j < 2; ++j)
                acc[i][j] = __builtin_amdgcn_mfma_f32_16x16x32_bf16(af[i], bfr[j], acc[i][j], 0, 0, 0);
        __syncthreads();
        cur ^= 1;
    }

#pragma unroll
    for (int i = 0; i < 2; ++i) {
        const int gr = br + wr + 16 * i + q * 4;
#pragma unroll
        for (int j = 0; j < 2; ++j) {
            const int gc = bc + wc + 16 * j + m16;
            if (gc < 1024) {
                const float b = bias[gc];
#pragma unroll
                for (int r = 0; r < 4; ++r)
                    C[(size_t)(gr + r) * 1024 + gc] = acc[i][j][r] + b;
            } else if (gc < 1039) {
                const float b = bias[gc];
#pragma unroll
                for (int r = 0; r < 4; ++r)
                    t[(size_t)(gr + r) * 15 + (gc - 1024)] = acc[i][j][r] + b;
            }
        }
    }
}

#define FB_TI 16
#define FB_JC 4
__global__ __launch_bounds__(256)
void diversity_kernel(const float* __restrict__ t, float* __restrict__ dv_part, int N) {
    const int tid = threadIdx.x;
    const int lane = tid & 63;
    const int g = tid >> 6;
    const int i0 = blockIdx.x * FB_TI + g * 4;
    const int jbeg = blockIdx.y * (N / FB_JC);
    const int jend = jbeg + N / FB_JC;

    float ti[4][15];
#pragma unroll
    for (int r = 0; r < 4; ++r)
#pragma unroll
        for (int d = 0; d < 15; ++d)
            ti[r][d] = t[(i0 + r) * 15 + d];

    float acc[4][5] = {};

    __shared__ float tj_s[256 * 15];
    for (int j0 = jbeg; j0 < jend; j0 += 256) {
        __syncthreads();
#pragma unroll
        for (int it = 0; it < 15; ++it)
            tj_s[it * 256 + tid] = t[j0 * 15 + it * 256 + tid];
        __syncthreads();
#pragma unroll
        for (int m = 0; m < 4; ++m) {
            const float* rp = tj_s + (m * 64 + lane) * 15;
            float tj[15];
#pragma unroll
            for (int d = 0; d < 15; ++d) tj[d] = rp[d];
#pragma unroll
            for (int r = 0; r < 4; ++r) {
#pragma unroll
                for (int k = 0; k < 5; ++k) {
                    const float s = fabsf(ti[r][3 * k]     - tj[3 * k])
                                  + fabsf(ti[r][3 * k + 1] - tj[3 * k + 1])
                                  + fabsf(ti[r][3 * k + 2] - tj[3 * k + 2]);
                    acc[r][k] += __expf(-s);
                }
            }
        }
    }

#pragma unroll
    for (int r = 0; r < 4; ++r)
#pragma unroll
        for (int k = 0; k < 5; ++k)
#pragma unroll
            for (int off = 32; off > 0; off >>= 1)
                acc[r][k] += __shfl_xor(acc[r][k], off, 64);

    if (lane == 0) {
        float* dst = dv_part + (size_t)blockIdx.y * N * 5;
#pragma unroll
        for (int r = 0; r < 4; ++r)
#pragma unroll
            for (int k = 0; k < 5; ++k)
                dst[(i0 + r) * 5 + k] = acc[r][k];
    }
}

__global__ void ln_lrelu_mid(const float* __restrict__ h,
                             const float* __restrict__ dv_part,
                             const float* __restrict__ beta,
                             unsigned short* __restrict__ out_bf,
                             int H, int D, int Cp, int M) {
    const int i = blockIdx.x;
    const int tid = threadIdx.x;
    const int C = H + D;
    float v[5];
    float s = 0.f, s2 = 0.f;
#pragma unroll
    for (int r = 0; r < 5; ++r) {
        const int c = tid + r * 256;
        if (c < C) {
            float x;
            if (c < H) x = h[(size_t)i * H + c];
            else {
                const int k = c - H;
                x = 0.f;
#pragma unroll
                for (int jc = 0; jc < FB_JC; ++jc)
                    x += dv_part[(size_t)jc * M * D + i * D + k];
            }
            v[r] = x; s += x; s2 += x * x;
        }
    }
    __shared__ float rs[4], rs2[4];
    const int lane = tid & 63, wave = tid >> 6;
#pragma unroll
    for (int off = 32; off > 0; off >>= 1) {
        s += __shfl_down(s, off, 64);
        s2 += __shfl_down(s2, off, 64);
    }
    if (lane == 0) { rs[wave] = s; rs2[wave] = s2; }
    __syncthreads();
    const float S = rs[0] + rs[1] + rs[2] + rs[3];
    const float S2 = rs2[0] + rs2[1] + rs2[2] + rs2[3];
    const float mu = S / (float)C;
    const float var = S2 / (float)C - mu * mu;
    const float rstd = rsqrtf(var + LN_EPS);
#pragma unroll
    for (int r = 0; r < 5; ++r) {
        const int c = tid + r * 256;
        if (c < C) {
            float y = (v[r] - mu) * rstd + beta[c];
            y = (y >= 0.f) ? y : LRELU_ALPHA * y;
            out_bf[(size_t)i * Cp + c] = f2bf(y);
        } else if (c < Cp) {
            out_bf[(size_t)i * Cp + c] = 0;
        }
    }
}

__global__ void ln_lrelu_head(const float* __restrict__ h,
                              const float* __restrict__ dv_part,
                              const float* __restrict__ beta, const float* __restrict__ wf,
                              const float* __restrict__ bfp, float* __restrict__ out,
                              int H, int D, int M) {
    const int i = blockIdx.x;
    const int tid = threadIdx.x;
    const int C = H + D;
    float v[5];
    float s = 0.f, s2 = 0.f;
#pragma unroll
    for (int r = 0; r < 5; ++r) {
        const int c = tid + r * 256;
        if (c < C) {
            float x;
            if (c < H) x = h[(size_t)i * H + c];
            else {
                const int k = c - H;
                x = 0.f;
#pragma unroll
                for (int jc = 0; jc < FB_JC; ++jc)
                    x += dv_part[(size_t)jc * M * D + i * D + k];
            }
            v[r] = x; s += x; s2 += x * x;
        }
    }
    __shared__ float rs[4], rs2[4], rh[4];
    const int lane = tid & 63, wave = tid >> 6;
#pragma unroll
    for (int off = 32; off > 0; off >>= 1) {
        s += __shfl_down(s, off, 64);
        s2 += __shfl_down(s2, off, 64);
    }
    if (lane == 0) { rs[wave] = s; rs2[wave] = s2; }
    __syncthreads();
    const float S = rs[0] + rs[1] + rs[2] + rs[3];
    const float S2 = rs2[0] + rs2[1] + rs2[2] + rs2[3];
    const float mu = S / (float)C;
    const float var = S2 / (float)C - mu * mu;
    const float rstd = rsqrtf(var + LN_EPS);
    float hsum = 0.f;
#pragma unroll
    for (int r = 0; r < 5; ++r) {
        const int c = tid + r * 256;
        if (c < C) {
            float y = (v[r] - mu) * rstd + beta[c];
            y = (y >= 0.f) ? y : LRELU_ALPHA * y;
            hsum += y * wf[c];
        }
    }
#pragma unroll
    for (int off = 32; off > 0; off >>= 1) hsum += __shfl_down(hsum, off, 64);
    if (lane == 0) rh[wave] = hsum;
    __syncthreads();
    if (tid == 0) out[i] = rh[0] + rh[1] + rh[2] + rh[3] + bfp[0];
}

// ===========================================================================
extern "C" void kernel_launch(void* const* d_in, const int* in_sizes, int n_in,
                              void* d_out, int out_size, void* d_ws, size_t ws_size,
                              hipStream_t stream) {
    const float* x     = (const float*)d_in[0];
    const float* w0a   = (const float*)d_in[1];
    const float* b0a   = (const float*)d_in[2];
    const float* w0b   = (const float*)d_in[3];
    const float* b0b   = (const float*)d_in[4];
    const float* beta0 = (const float*)d_in[5];
    const float* w1a   = (const float*)d_in[6];
    const float* b1a   = (const float*)d_in[7];
    const float* w1b   = (const float*)d_in[8];
    const float* b1b   = (const float*)d_in[9];
    const float* beta1 = (const float*)d_in[10];
    const float* wf    = (const float*)d_in[11];
    const float* bf    = (const float*)d_in[12];
    float* out = (float*)d_out;

    const int M = 4096, NF = 512, HID = 1024, CP = 1056;

    // fp32 workspace (all offsets multiple-of-4 floats -> 16B aligned)
    float* h   = (float*)d_ws;                      // 4096 x 1024
    float* t   = h   + (size_t)M * HID;             // 4096 x 15 (contiguous)
    float* dvp = t   + (size_t)M * 15;              // 4 x 4096 x 5 (mega uses 2 slots)
    float* be0 = dvp + (size_t)4 * M * 5;           // 1152
    float* be1 = be0 + NE;                          // 1152
    unsigned short* x_bf  = (unsigned short*)(be1 + NE);             // 4096 x 512
    unsigned short* hc_bf = x_bf + (size_t)M * NF;                   // 4096 x 1056
    unsigned short* bT0   = hc_bf + (size_t)M * CP;                  // 1152 x 512
    unsigned short* bT1   = bT0 + (size_t)NE * NF;                   // 1152 x 1056

    // ---- preferred path: single cooperative kernel ----
    void* args[] = { (void*)&x, (void*)&w0a, (void*)&b0a, (void*)&w0b, (void*)&b0b,
                     (void*)&w1a, (void*)&b1a, (void*)&w1b, (void*)&b1b,
                     (void*)&beta0, (void*)&beta1, (void*)&wf, (void*)&bf,
                     (void*)&out, (void*)&h, (void*)&t, (void*)&dvp,
                     (void*)&be0, (void*)&be1,
                     (void*)&x_bf, (void*)&hc_bf, (void*)&bT0, (void*)&bT1 };
    hipError_t e = hipLaunchCooperativeKernel(reinterpret_cast<void*>(mega_kernel),
                                              dim3(NB), dim3(256), args, 0, stream);
    if (e == hipSuccess) return;

    // ---- fallback: proven Round-1 8-kernel pipeline ----
    prep_kernel<<<4011, 256, 0, stream>>>(x, w0a, b0a, w0b, b0b, w1a, b1a, w1b, b1b,
                                          x_bf, bT0, bT1, be0, be1);
    mfma_gemm<<<dim3(NE / 64, M / 64), 256, 0, stream>>>(x_bf, NF, bT0, NF, be0, h, t, NF);
    diversity_kernel<<<dim3(M / FB_TI, FB_JC), 256, 0, stream>>>(t, dvp, M);
    ln_lrelu_mid<<<M, 256, 0, stream>>>(h, dvp, beta0, hc_bf, HID, 5, CP, M);
    mfma_gemm<<<dim3(NE / 64, M / 64), 256, 0, stream>>>(hc_bf, CP, bT1, CP, be1, h, t, CP);
    diversity_kernel<<<dim3(M / FB_TI, FB_JC), 256, 0, stream>>>(t, dvp, M);
    ln_lrelu_head<<<M, 256, 0, stream>>>(h, dvp, beta1, wf, bf, out, HID, 5, M);
}